// Round 16
// baseline (4788.256 us; speedup 1.0000x reference)
//
#include <hip/hip_runtime.h>
#include <hip/hip_bf16.h>
#include <math.h>

// Problem constants
constexpr int B = 128;
constexpr int T = 256;
constexpr int H = 200;       // hidden
constexpr int G4 = 800;      // 4*H
constexpr int BT = B * T;    // 32768
constexpr int K0 = 360, K0P = 384;   // layer0 input dim, padded to %32
constexpr int K1 = 400, K1P = 416;   // layer1 input dim, padded to %32

typedef __bf16 bf16x8 __attribute__((ext_vector_type(8)));
typedef _Float16 f16x8 __attribute__((ext_vector_type(8)));
typedef float f32x4 __attribute__((ext_vector_type(4)));
typedef unsigned uix4 __attribute__((ext_vector_type(4)));

__device__ __forceinline__ float bfr2f(unsigned short u) {
  union { unsigned int i; float f; } x;
  x.i = ((unsigned int)u) << 16;
  return x.f;
}
__device__ __forceinline__ float sigm(float x) {
  return 1.0f / (1.0f + __expf(-x));
}
__device__ __forceinline__ float tanh_f(float x) {
  float e = __expf(2.0f * x);
  return (e - 1.0f) / (e + 1.0f);
}
// flag-dispatched raw load of a "float" input (f32 or bf16 storage)
__device__ __forceinline__ float ldraw(const void* p, size_t i, int f) {
  return f ? ((const float*)p)[i] : bfr2f(((const unsigned short*)p)[i]);
}

// Direct global->LDS 16B copy (gfx950); verified round 14/15.
__device__ __forceinline__ void glds16(const void* g, void* l) {
  __builtin_amdgcn_global_load_lds(
      (const __attribute__((address_space(1))) unsigned int*)g,
      (__attribute__((address_space(3))) unsigned int*)l, 16, 0, 0);
}

// ---------------------------------------------------------------------------
// Dtype detector (f32 vs bf16 storage of float inputs).
__global__ void detect_dtype(const unsigned short* __restrict__ raw,
                             int* __restrict__ flag) {
  __shared__ int cnt[256];
  int c = 0;
  for (int j = 0; j < 32; ++j) {
    unsigned short u = raw[1024 + threadIdx.x * 32 + j];
    int e = (u >> 7) & 0xFF;
    if (e >= 0xC0) ++c;
  }
  cnt[threadIdx.x] = c;
  __syncthreads();
  for (int off = 128; off > 0; off >>= 1) {
    if (threadIdx.x < off) cnt[threadIdx.x] += cnt[threadIdx.x + off];
    __syncthreads();
  }
  if (threadIdx.x == 0) *flag = (cnt[0] > 16) ? 1 : 0;
}

// ---------------------------------------------------------------------------
// Merged prep. Round-16 layout:
//  [0,2500):      W_hh -> fp16 [4][800][200] row-major (Wmf; fp16 exact for
//                 bf16-derived weights; feeds mfma_f32_16x16x32_f16 B-frags)
//  [2500,4100):   pad-copy W_ih layer0 -> [1600][K0P] bf16
//  [4100,5700):   pad-copy W_ih layer1 -> [1600][K1P] bf16
//  [5700,9796):   embed 8 tokens/block into X0
//  [9796,11844):  grid-stride zero-fill of X1 and RNN
//  [11844,11857): biascat f32 [2 layers][1600] (dir-concat; added in the
//                 GEMM epilogue so Gpre carries x@W_ih^T + bias)
__global__ __launch_bounds__(256) void prep_all(
    const void* __restrict__ whh0, const void* __restrict__ whh1,
    const void* __restrict__ whh2, const void* __restrict__ whh3,
    _Float16* __restrict__ wmf,
    const void* __restrict__ wih0f, const void* __restrict__ wih0b,
    __hip_bfloat16* __restrict__ wih0p,
    const void* __restrict__ wih1f, const void* __restrict__ wih1b,
    __hip_bfloat16* __restrict__ wih1p,
    const int* __restrict__ words,
    const int* __restrict__ pos,
    const int* __restrict__ ner,
    const void* __restrict__ emb_w,
    const void* __restrict__ pos_w,
    const void* __restrict__ ner_w,
    __hip_bfloat16* __restrict__ X0,
    uix4* __restrict__ z0, size_t n0,   // X1 region (uix4 count)
    uix4* __restrict__ z1, size_t n1,   // RNN region
    const void* __restrict__ b0f, const void* __restrict__ b0b,
    const void* __restrict__ b1f, const void* __restrict__ b1b,
    float* __restrict__ biascat,        // [2][1600]
    const int* __restrict__ flag) {
  int blk = blockIdx.x;
  int f = *flag;
  if (blk < 2500) {
    int idx = blk * 256 + threadIdx.x;  // 4*800*200 = 640000
    if (idx >= 640000) return;
    int m = idx / 160000;
    int loc = idx - m * 160000;
    const void* src = (m == 0) ? whh0 : (m == 1) ? whh1 : (m == 2) ? whh2 : whh3;
    wmf[idx] = (_Float16)ldraw(src, loc, f);
  } else if (blk < 4100) {
    int r = blk - 2500;  // 0..1599
    const void* src = (r < G4) ? wih0f : wih0b;
    int rr = (r < G4) ? r : r - G4;
    for (int j = threadIdx.x; j < K0P; j += 256) {
      float v = (j < K0) ? ldraw(src, (size_t)rr * K0 + j, f) : 0.0f;
      wih0p[(size_t)r * K0P + j] = __float2bfloat16(v);
    }
  } else if (blk < 5700) {
    int r = blk - 4100;  // 0..1599
    const void* src = (r < G4) ? wih1f : wih1b;
    int rr = (r < G4) ? r : r - G4;
    for (int j = threadIdx.x; j < K1P; j += 256) {
      float v = (j < K1) ? ldraw(src, (size_t)rr * K1 + j, f) : 0.0f;
      wih1p[(size_t)r * K1P + j] = __float2bfloat16(v);
    }
  } else if (blk < 9796) {
    int bt = (blk - 5700) * 8 + (threadIdx.x >> 5);
    int j0 = threadIdx.x & 31;
    int w = words[bt], p = pos[bt], nr = ner[bt];
    for (int j = j0; j < K0P; j += 32) {
      float v;
      if (j < 300)       v = ldraw(emb_w, (size_t)w * 300 + j, f);
      else if (j < 330)  v = ldraw(pos_w, (size_t)p * 30 + (j - 300), f);
      else if (j < 360)  v = ldraw(ner_w, (size_t)nr * 30 + (j - 330), f);
      else               v = 0.0f;
      X0[(size_t)bt * K0P + j] = __float2bfloat16(v);
    }
  } else if (blk < 11844) {
    size_t i = (size_t)(blk - 9796) * 256 + threadIdx.x;
    size_t stride = (size_t)2048 * 256;
    uix4 z = {0u, 0u, 0u, 0u};
    size_t nt = n0 + n1;
    for (; i < nt; i += stride) {
      if (i < n0) z0[i] = z;
      else        z1[i - n0] = z;
    }
  } else {
    int idx = (blk - 11844) * 256 + threadIdx.x;  // 3200
    if (idx >= 3200) return;
    int l = idx / 1600, rest = idx - l * 1600;
    int d = rest / 800, g = rest - d * 800;
    const void* src = (l == 0) ? (d == 0 ? b0f : b0b) : (d == 0 ? b1f : b1b);
    biascat[idx] = ldraw(src, g, f);
  }
}

// ---------------------------------------------------------------------------
// MFMA GEMM v5.1 (verified round 15) + bias epilogue: single-buffered 128x128
// tile, BK=64, glds staging, XOR-swizzled, XCD-aware decode, 4 blocks/CU.
// Epilogue adds biascat[col] so Gpre = x@W_ih^T + bias (lstm no longer adds).
__global__ __launch_bounds__(256) void gemm_bt(
    const __hip_bfloat16* __restrict__ A,
    const __hip_bfloat16* __restrict__ Bm,
    __hip_bfloat16* __restrict__ C,
    int N, int Kp,
    const float* __restrict__ biasv) {
  const int tid = threadIdx.x;
  const int lane = tid & 63;
  const int wave = tid >> 6;           // 0..3
  const int l15 = lane & 15, quad = lane >> 4;
  const int wr = wave & 1, wc = wave >> 1;   // 2x2 wave grid, 64x64 each

  const int blk = blockIdx.x;
  const int x = blk & 7, j = blk >> 3;
  const int m0 = (x + 8 * (j / 13)) * 128;
  const int n0 = (j % 13) * 128;

  __shared__ __align__(16) __hip_bfloat16 Ab[128 * 64];
  __shared__ __align__(16) __hip_bfloat16 Bb[128 * 64];

  f32x4 acc[4][4] = {};

  const int nk_full = Kp >> 6;                    // 384->6, 416->6
  const int nk = nk_full + ((Kp & 63) ? 1 : 0);   // 384->6, 416->7

  for (int kt = 0; kt < nk; ++kt) {
    if (kt < nk_full) {
      const int k0 = kt << 6;
      #pragma unroll
      for (int jj = 0; jj < 4; ++jj) {
        int c = tid + jj * 256;
        int row = c >> 3, p = c & 7;
        int qd = p ^ (row & 7);
        glds16(A + (size_t)(m0 + row) * Kp + k0 + qd * 8,
               (char*)&Ab[0] + c * 16);
        int br = n0 + row; if (br > N - 1) br = N - 1;
        glds16(Bm + (size_t)br * Kp + k0 + qd * 8,
               (char*)&Bb[0] + c * 16);
      }
    } else {
      const int k0 = nk_full << 6;
      #pragma unroll
      for (int jj = 0; jj < 8; ++jj) {
        int c = tid + (jj & 3) * 256;
        int row = c >> 3, p = c & 7;
        int qd = p ^ (row & 7);
        int kcol = k0 + qd * 8;
        uix4 v = {0u, 0u, 0u, 0u};
        if (kcol + 8 <= Kp) {
          if (jj < 4) {
            v = *(const uix4*)(A + (size_t)(m0 + row) * Kp + kcol);
          } else {
            int br = n0 + row; if (br > N - 1) br = N - 1;
            v = *(const uix4*)(Bm + (size_t)br * Kp + kcol);
          }
        }
        if (jj < 4) *(uix4*)((char*)&Ab[0] + c * 16) = v;
        else        *(uix4*)((char*)&Bb[0] + c * 16) = v;
      }
    }
    __syncthreads();

    #pragma unroll
    for (int k32 = 0; k32 < 2; ++k32) {
      bf16x8 a[4], b[4];
      #pragma unroll
      for (int mi = 0; mi < 4; ++mi) {
        int row = wr * 64 + mi * 16 + l15;
        int p = (k32 * 4 + quad) ^ (row & 7);
        a[mi] = *(const bf16x8*)((const char*)&Ab[0] + (row * 8 + p) * 16);
      }
      #pragma unroll
      for (int ni = 0; ni < 4; ++ni) {
        int row = wc * 64 + ni * 16 + l15;
        int p = (k32 * 4 + quad) ^ (row & 7);
        b[ni] = *(const bf16x8*)((const char*)&Bb[0] + (row * 8 + p) * 16);
      }
      #pragma unroll
      for (int mi = 0; mi < 4; ++mi)
        #pragma unroll
        for (int ni = 0; ni < 4; ++ni)
          acc[mi][ni] = __builtin_amdgcn_mfma_f32_16x16x32_bf16(
              a[mi], b[ni], acc[mi][ni], 0, 0, 0);
    }
    __syncthreads();
  }

  #pragma unroll
  for (int mi = 0; mi < 4; ++mi)
    #pragma unroll
    for (int ni = 0; ni < 4; ++ni)
      #pragma unroll
      for (int r = 0; r < 4; ++r) {
        int row = m0 + wr * 64 + mi * 16 + quad * 4 + r;
        int col = n0 + wc * 64 + ni * 16 + l15;
        if (col < N)
          C[(size_t)row * N + col] = __float2bfloat16(acc[mi][ni][r] + biasv[col]);
      }
}

// ---------------------------------------------------------------------------
// LSTM recurrence v12 (MFMA): 16 blocks (rg = blk&7 row-group of 16 rows,
// dir = blk>>3), 512 threads / 8 waves. Round 15 post-mortem: v7's floor
// (357 µs, MfmaUtil 0, VALUBusy 43%) is structural — VALU dot2 + cross-wave
// reduce. v12 batches 16 rows and computes h@W_hh^T per step as an MFMA GEMM
// (M=16 rows, N=800 gates, K=200->224): reduction lives in the MFMA K-dim
// (NO cross-wave reduce), gates split N-wise across waves (100 each, 7
// 16-tiles, clamp/guard for the 112-slot overhang), W_hh resident in regs
// as 49 f16x8 B-frags (~196 VGPR; MFMA reads AGPRs natively). fp16 MFMA
// keeps numerics = v7's fdot2 path. Masked update replaces length-skip
// (group max-len kept). Bias pre-added into Gpre by the GEMM epilogue.
// Fragment mappings identical to the verified gemm_bt.
__global__ __launch_bounds__(512, 2) void lstm_mfma(
    const __hip_bfloat16* __restrict__ Gpre,   // [B*T][1600] x@W_ih^T + bias
    const _Float16* __restrict__ Wmf,          // [2 dirs][800][200] fp16
    const int* __restrict__ masks,             // [B][T], 1 = pad
    __hip_bfloat16* __restrict__ out,          // [B][T][ostride] (pre-zeroed)
    int ostride,
    float* __restrict__ final_h)               // [B][400] = [hb | hf], or null
{
  const int tid = threadIdx.x;
  const int lane = tid & 63;
  const int wave = tid >> 6;        // 0..7
  const int l15 = lane & 15, quad = lane >> 4;
  const int dir = blockIdx.x >> 3;
  const int rgbase = (blockIdx.x & 7) * 16;
  const int wbase = wave * 100;     // this wave's gate span [wbase, wbase+100)

  __shared__ __align__(16) _Float16 hsh[16][232];  // h tile, k-pad 200..231 = 0
                                                   // stride 232: bank period 8
  __shared__ float gsh[16][804];                   // gates f32
  __shared__ int   msh[16][256];                   // masks tile
  __shared__ int   lred[256];                      // maxlen reduce

  // --- zero h (incl. pad cols), stage masks ---
  for (int i = tid; i < 16 * 232; i += 512) ((_Float16*)hsh)[i] = (_Float16)0.0f;
  for (int i = tid; i < 16 * 256; i += 512) {
    int r = i >> 8, t = i & 255;
    msh[r][t] = masks[(rgbase + r) * T + t];
  }

  // --- W_hh B-frags: 7 tiles x 7 kslices, loaded once ---
  // B-frag (verified gemm layout): lane holds W[gate = base+nt*16+l15]
  // [k = ks*32 + quad*8 .. +7]. K storage is 200: kslice 6 covers k 192..223,
  // real only for quad 0 (k 192..199); quads 1-3 are the zero pad.
  // Gate overhang (slots 100..111) clamped to row 799; stores are guarded.
  f16x8 wf[7][7];
  {
    const _Float16* wsl = Wmf + (size_t)dir * 160000;
    #pragma unroll
    for (int nt = 0; nt < 7; ++nt) {
      int g = wbase + nt * 16 + l15;
      if (g > 799) g = 799;
      const _Float16* wrow = wsl + (size_t)g * 200;
      #pragma unroll
      for (int ks = 0; ks < 7; ++ks) {
        if (ks < 6)          wf[nt][ks] = *(const f16x8*)(wrow + ks * 32 + quad * 8);
        else if (quad == 0)  wf[nt][ks] = *(const f16x8*)(wrow + 192);
        else                 wf[nt][ks] = f16x8{};
      }
    }
  }
  __syncthreads();

  // --- group max length: #t where ANY of the 16 rows is unpadded ---
  if (tid < 256) {
    int any = 0;
    #pragma unroll
    for (int r = 0; r < 16; ++r) any |= (msh[r][tid] == 0);
    lred[tid] = any ? 1 : 0;
  }
  __syncthreads();
  for (int off = 128; off > 0; off >>= 1) {
    if (tid < off) lred[tid] += lred[tid + off];
    __syncthreads();
  }
  const int maxlen = lred[0];

  const unsigned short* gp = (const unsigned short*)Gpre + dir * 800;
  float creg[7] = {};   // c state, thread-owned (static (row,unit) map)

  #pragma unroll 1
  for (int tt = 0; tt < maxlen; ++tt) {
    const int t = dir ? (maxlen - 1 - tt) : tt;

    // --- Gpre prefetch to regs (in flight across the MFMA phase) ---
    unsigned short q0[7], q1[7], q2[7], q3[7];
    #pragma unroll
    for (int j = 0; j < 7; ++j) {
      int p = tid + j * 512;
      if (p < 3200) {
        int row = p / 200, u = p - row * 200;
        const unsigned short* gq =
            gp + ((size_t)(rgbase + row) * T + t) * 1600 + u;
        q0[j] = gq[0]; q1[j] = gq[200]; q2[j] = gq[400]; q3[j] = gq[600];
      } else { q0[j] = q1[j] = q2[j] = q3[j] = 0; }
    }

    // --- MFMA: gates[16 rows][this wave's 112 gate-slots] ---
    f32x4 vac[7] = {};
    #pragma unroll
    for (int ks = 0; ks < 7; ++ks) {
      const f16x8 af = *(const f16x8*)((const char*)hsh +
                         (l15 * 232 + ks * 32 + quad * 8) * 2);
      #pragma unroll
      for (int nt = 0; nt < 7; ++nt)
        vac[nt] = __builtin_amdgcn_mfma_f32_16x16x32_f16(
            af, wf[nt][ks], vac[nt], 0, 0, 0);
    }
    #pragma unroll
    for (int nt = 0; nt < 7; ++nt) {
      int gl = nt * 16 + l15;
      if (gl < 100) {                       // guard overhang + clamp dups
        int g = wbase + gl;
        #pragma unroll
        for (int r = 0; r < 4; ++r)
          gsh[quad * 4 + r][g] = vac[nt][r];   // C: row=(lane>>4)*4+r, col=l15
      }
    }
    __syncthreads();

    // --- nonlinearity + masked state update; (row,unit) = p static map ---
    #pragma unroll
    for (int j = 0; j < 7; ++j) {
      int p = tid + j * 512;
      if (p < 3200) {
        int row = p / 200, u = p - row * 200;
        float mt = (msh[row][t] == 0) ? 1.0f : 0.0f;
        float gi = gsh[row][u]       + bfr2f(q0[j]);
        float gf = gsh[row][200 + u] + bfr2f(q1[j]);
        float gg = gsh[row][400 + u] + bfr2f(q2[j]);
        float go = gsh[row][600 + u] + bfr2f(q3[j]);
        float si = sigm(gi), sf = sigm(gf), so = sigm(go);
        float cn = sf * creg[j] + si * tanh_f(gg);
        float hn = so * tanh_f(cn);
        creg[j] = mt * cn + (1.0f - mt) * creg[j];
        float hold = (float)hsh[row][u];
        hsh[row][u] = (_Float16)(mt * hn + (1.0f - mt) * hold);
        out[((size_t)(rgbase + row) * T + t) * ostride + dir * H + u] =
            __float2bfloat16(mt * hn);
      }
    }
    __syncthreads();
  }

  if (final_h != nullptr) {
    #pragma unroll
    for (int j = 0; j < 7; ++j) {
      int p = tid + j * 512;
      if (p < 3200) {
        int row = p / 200, u = p - row * 200;
        int col = dir ? u : (H + u);
        final_h[(size_t)(rgbase + row) * 400 + col] = (float)hsh[row][u];
      }
    }
  }
}

// ---------------------------------------------------------------------------
// Span sums v2 (verified): chunked (t-chunk x d-octet), bf16x8 row loads.
__global__ __launch_bounds__(256) void span_sum(
    const __hip_bfloat16* __restrict__ rnn,   // [B][T][400]
    const int* __restrict__ masks,
    const int* __restrict__ subj_pos,
    const int* __restrict__ obj_pos,
    float* __restrict__ obj_h,   // [B][400]
    float* __restrict__ subj_h)  // [B][400]
{
  int b = blockIdx.x;
  int tc = threadIdx.x >> 6;
  int dv = threadIdx.x & 63;
  __shared__ float aS[4][400];
  __shared__ float aO[4][400];

  float ss[8] = {}, so[8] = {};
  if (dv < 50) {
    for (int t = tc * 64; t < tc * 64 + 64; ++t) {
      int m = masks[b * T + t];
      int fs = (subj_pos[b * T + t] + m) == 0;
      int fo = (obj_pos[b * T + t] + m) == 0;
      if (fs | fo) {
        uix4 v = *(const uix4*)(rnn + ((size_t)b * T + t) * 400 + dv * 8);
        #pragma unroll
        for (int j = 0; j < 4; ++j) {
          float lo = bfr2f((unsigned short)(v[j] & 0xFFFF));
          float hi = bfr2f((unsigned short)(v[j] >> 16));
          if (fs) { ss[2 * j] += lo; ss[2 * j + 1] += hi; }
          if (fo) { so[2 * j] += lo; so[2 * j + 1] += hi; }
        }
      }
    }
    #pragma unroll
    for (int k = 0; k < 8; ++k) {
      aS[tc][dv * 8 + k] = ss[k];
      aO[tc][dv * 8 + k] = so[k];
    }
  }
  __syncthreads();
  for (int d = threadIdx.x; d < 400; d += 256) {
    subj_h[(size_t)b * 400 + d] = aS[0][d] + aS[1][d] + aS[2][d] + aS[3][d];
    obj_h[(size_t)b * 400 + d]  = aO[0][d] + aO[1][d] + aO[2][d] + aO[3][d];
  }
}

// ---------------------------------------------------------------------------
// Single-query attention pooling v2 (verified). grid = 3*128.
__global__ __launch_bounds__(256) void attn_pool_k(
    const float* __restrict__ qbuf,           // [3][B][400]
    const __hip_bfloat16* __restrict__ rnn,   // [B][T][400]
    const int* __restrict__ masks,
    float* __restrict__ outp)                 // [3][B][400]
{
  int b = blockIdx.x & 127;
  int qi = blockIdx.x >> 7;
  __shared__ float qs[400];
  __shared__ float ps[256];
  __shared__ float red[256];
  __shared__ float acc4[4][400];
  const float* q = qbuf + ((size_t)qi * B + b) * 400;
  for (int d = threadIdx.x; d < 400; d += 256) qs[d] = q[d];
  __syncthreads();

  int t = threadIdx.x;
  const uix4* kvv = (const uix4*)(rnn + ((size_t)b * T + t) * 400);
  float s = 0.f;
  #pragma unroll 5
  for (int i = 0; i < 50; ++i) {
    uix4 v = kvv[i];
    #pragma unroll
    for (int j = 0; j < 4; ++j) {
      s += bfr2f((unsigned short)(v[j] & 0xFFFF)) * qs[8 * i + 2 * j];
      s += bfr2f((unsigned short)(v[j] >> 16))    * qs[8 * i + 2 * j + 1];
    }
  }
  s *= 0.05f;  // 1/sqrt(400)
  if (masks[b * T + t] != 0) s = -1e9f;

  red[t] = s;
  __syncthreads();
  for (int off = 128; off > 0; off >>= 1) {
    if (t < off) red[t] = fmaxf(red[t], red[t + off]);
    __syncthreads();
  }
  float mx = red[0];
  __syncthreads();
  float e = expf(s - mx);
  red[t] = e;
  __syncthreads();
  for (int off = 128; off > 0; off >>= 1) {
    if (t < off) red[t] += red[t + off];
    __syncthreads();
  }
  float inv = 1.0f / red[0];
  ps[t] = e * inv;
  __syncthreads();

  int tc = threadIdx.x >> 6;
  int dv = threadIdx.x & 63;
  float a[8] = {};
  if (dv < 50) {
    for (int t2 = tc * 64; t2 < tc * 64 + 64; ++t2) {
      float wgt = ps[t2];
      if (wgt != 0.f) {
        uix4 v = *(const uix4*)(rnn + ((size_t)b * T + t2) * 400 + dv * 8);
        #pragma unroll
        for (int j = 0; j < 4; ++j) {
          a[2 * j]     += wgt * bfr2f((unsigned short)(v[j] & 0xFFFF));
          a[2 * j + 1] += wgt * bfr2f((unsigned short)(v[j] >> 16));
        }
      }
    }
    #pragma unroll
    for (int k = 0; k < 8; ++k) acc4[tc][dv * 8 + k] = a[k];
  }
  __syncthreads();
  for (int d = threadIdx.x; d < 400; d += 256)
    outp[((size_t)qi * B + b) * 400 + d] =
        acc4[0][d] + acc4[1][d] + acc4[2][d] + acc4[3][d];
}

// ---------------------------------------------------------------------------
// Head — reads all weights raw (flag-dispatched), writes bf16 or f32 per flag
__global__ __launch_bounds__(256) void final_head(
    const float* __restrict__ attn,   // [3][B][400]: 0=obj,1=subj,2=glob
    const void* __restrict__ wo_w, const void* __restrict__ wo_b,
    const void* __restrict__ ws_w, const void* __restrict__ ws_b,
    const void* __restrict__ wg_w, const void* __restrict__ wg_b,
    const void* __restrict__ cls_w, const void* __restrict__ cls_b,
    void* __restrict__ outp,          // [B][2]
    const int* __restrict__ flag)
{
  int b = blockIdx.x;
  int f = *flag;
  __shared__ float hs[H];
  int j = threadIdx.x;
  if (j < H) {
    float acc = ldraw(wo_b, j, f) + ldraw(ws_b, j, f) + ldraw(wg_b, j, f);
    const float* oa = attn + ((size_t)0 * B + b) * 400;
    const float* sa = attn + ((size_t)1 * B + b) * 400;
    const float* ga = attn + ((size_t)2 * B + b) * 400;
    for (int d = 0; d < 400; ++d) {
      acc += oa[d] * ldraw(wo_w, (size_t)j * 400 + d, f);
      acc += sa[d] * ldraw(ws_w, (size_t)j * 400 + d, f);
      acc += ga[d] * ldraw(wg_w, (size_t)j * 400 + d, f);
    }
    hs[j] = fmaxf(acc, 0.0f);
  }
  __syncthreads();
  if (j < 2) {
    float a = ldraw(cls_b, j, f);
    for (int k = 0; k < H; ++k)
      a += hs[k] * ldraw(cls_w, (size_t)j * H + k, f);
    if (f) ((float*)outp)[b * 2 + j] = a;
    else   ((__hip_bfloat16*)outp)[b * 2 + j] = __float2bfloat16(a);
  }
}

// ---------------------------------------------------------------------------
// Workspace layout (bytes)
constexpr size_t O_X0   = 0;            // 32768*384*2  = 25165824
constexpr size_t O_X1   = 25165824;     // 32768*416*2  = 27262976
constexpr size_t O_GPRE = 52428800;     // 32768*1600*2 = 104857600
constexpr size_t O_RNN  = 157286400;    // 32768*400*2  = 26214400
constexpr size_t O_WIH0 = 183500800;    // 1600*384*2   = 1228800
constexpr size_t O_WIH1 = 184729600;    // 1600*416*2   = 1331200
constexpr size_t O_WPK  = 186060800;    // 4*800*200*2  = 1280000 (Wmf fp16)
constexpr size_t O_Q    = 187340800;    // 3*128*400*4  = 614400
                                        // (first 12800 B double as biascat
                                        //  until span_sum overwrites; dead
                                        //  after gemm layer 1)
constexpr size_t O_ATT  = 187955200;    // 614400
constexpr size_t O_FLAG = 188569600;    // 256

extern "C" void kernel_launch(void* const* d_in, const int* in_sizes, int n_in,
                              void* d_out, int out_size, void* d_ws, size_t ws_size,
                              hipStream_t stream) {
  (void)in_sizes; (void)n_in; (void)out_size; (void)ws_size;

  const int* words = (const int*)d_in[0];
  const int* masks = (const int*)d_in[1];
  const int* pos   = (const int*)d_in[2];
  const int* ner   = (const int*)d_in[3];
  const int* subj  = (const int*)d_in[4];
  const int* obj   = (const int*)d_in[5];
  const void* emb_w = d_in[6];
  const void* pos_w = d_in[7];
  const void* ner_w = d_in[8];
  const void* wih[4]  = {d_in[9],  d_in[12], d_in[15], d_in[18]};
  const void* whh[4]  = {d_in[10], d_in[13], d_in[16], d_in[19]};
  const void* bias[4] = {d_in[11], d_in[14], d_in[17], d_in[20]};
  const void* wo_w = d_in[21]; const void* wo_b = d_in[22];
  const void* ws_w = d_in[23]; const void* ws_b = d_in[24];
  const void* wg_w = d_in[25]; const void* wg_b = d_in[26];
  const void* cls_w = d_in[27]; const void* cls_b = d_in[28];

  char* ws = (char*)d_ws;
  __hip_bfloat16* X0   = (__hip_bfloat16*)(ws + O_X0);
  __hip_bfloat16* X1   = (__hip_bfloat16*)(ws + O_X1);
  __hip_bfloat16* Gpre = (__hip_bfloat16*)(ws + O_GPRE);   // [BT][1600]
  __hip_bfloat16* RNN  = (__hip_bfloat16*)(ws + O_RNN);
  __hip_bfloat16* wih0p = (__hip_bfloat16*)(ws + O_WIH0);  // [1600][384]
  __hip_bfloat16* wih1p = (__hip_bfloat16*)(ws + O_WIH1);  // [1600][416]
  _Float16* Wmf = (_Float16*)(ws + O_WPK);                 // [4][800][200] fp16
  float* qbuf = (float*)(ws + O_Q);    // [3][B][400]: obj, subj, glob
  float* biascat = qbuf;               // [2][1600] f32, dead after gemm1
  float* attb = (float*)(ws + O_ATT);  // [3][B][400]
  int* flag = (int*)(ws + O_FLAG);

  // --- dtype detect + fully-merged prep ---
  detect_dtype<<<1, 256, 0, stream>>>((const unsigned short*)emb_w, flag);
  prep_all<<<11857, 256, 0, stream>>>(
      whh[0], whh[1], whh[2], whh[3], Wmf,
      wih[0], wih[1], wih0p, wih[2], wih[3], wih1p,
      words, pos, ner, emb_w, pos_w, ner_w, X0,
      (uix4*)X1, (size_t)BT * K1P * 2 / 16,
      (uix4*)RNN, (size_t)BT * 400 * 2 / 16,
      bias[0], bias[1], bias[2], bias[3], biascat,
      flag);

  const int ggrid = (BT / 128) * 13;   // 3328, XCD-aware decode in-kernel

  // --- layer 0 ---
  gemm_bt<<<ggrid, 256, 0, stream>>>(X0, wih0p, Gpre, 1600, K0P, biascat);
  lstm_mfma<<<16, 512, 0, stream>>>(Gpre, Wmf, masks, X1, K1P, nullptr);

  // --- layer 1 ---
  gemm_bt<<<ggrid, 256, 0, stream>>>(X1, wih1p, Gpre, 1600, K1P, biascat + 1600);
  float* qglob = qbuf + (size_t)2 * B * 400;
  lstm_mfma<<<16, 512, 0, stream>>>(Gpre, Wmf + (size_t)2 * 160000, masks,
                                    RNN, 400, qglob);

  // --- span sums (obj -> slot0, subj -> slot1) ---
  span_sum<<<B, 256, 0, stream>>>(RNN, masks, subj, obj,
                                  qbuf, qbuf + (size_t)B * 400);

  // --- attention pooling (3 queries, v2) ---
  attn_pool_k<<<3 * B, 256, 0, stream>>>(qbuf, RNN, masks, attb);

  // --- head (raw weights) ---
  final_head<<<B, 256, 0, stream>>>(attb, wo_w, wo_b, ws_w, ws_b, wg_w, wg_b,
                                    cls_w, cls_b, d_out, flag);
}